// Round 13
// baseline (80.997 us; speedup 1.0000x reference)
//
#include <hip/hip_runtime.h>
#include <hip/hip_bf16.h>

// Problem constants (B=4, L=4096, C=512, H=16, Dh=32, K=13)
#define BATCH   4
#define LSEQ    4096
#define CCH     512
#define HNUM    16
#define DH      32
#define KSZ     13
#define NHALF   6           // K/2
#define M_TOT   16384       // B*L
#define N_QKV   1536        // 3*C
#define KDIM    512         // C
#define BK      64          // GEMM K-step (128B rows, XOR-swizzle domain of 8 chunks)

typedef __attribute__((ext_vector_type(8))) short  short8;
typedef __attribute__((ext_vector_type(4))) short  short4_t;
typedef __attribute__((ext_vector_type(4))) float  float4_t;

__device__ __forceinline__ unsigned short f32_to_bf16(float f) {
    union { float f; unsigned int u; } un; un.f = f;
    unsigned int u = un.u;
    u += 0x7FFFu + ((u >> 16) & 1u);   // RNE (inputs are finite)
    return (unsigned short)(u >> 16);
}
__device__ __forceinline__ float bf16_to_f32(unsigned short h) {
    union { unsigned int u; float f; } un; un.u = ((unsigned int)h) << 16;
    return un.f;
}

// async global(16B/lane) -> LDS; lds base must be wave-uniform, HW adds lane*16
__device__ __forceinline__ void gload_lds16(const unsigned short* g, unsigned short* l) {
    __builtin_amdgcn_global_load_lds(
        (const __attribute__((address_space(1))) unsigned int*)g,
        (__attribute__((address_space(3))) unsigned int*)l,
        16, 0, 0);
}

// ---------------------------------------------------------------- cvt f32->bf16
__global__ void cvt_all(const float4_t* __restrict__ xin,  short4_t* __restrict__ xo,  int nx,
                        const float4_t* __restrict__ w1in, short4_t* __restrict__ w1o, int n1,
                        const float4_t* __restrict__ w2in, short4_t* __restrict__ w2o, int n2) {
    int i = blockIdx.x * blockDim.x + threadIdx.x;
    int stride = gridDim.x * blockDim.x;
    int ntot = nx + n1 + n2;
    for (; i < ntot; i += stride) {
        const float4_t* src; short4_t* dst; int j;
        if (i < nx)            { src = xin;  dst = xo;  j = i; }
        else if (i < nx + n1)  { src = w1in; dst = w1o; j = i - nx; }
        else                   { src = w2in; dst = w2o; j = i - nx - n1; }
        float4_t v = src[j];
        short4_t h;
        h.x = (short)f32_to_bf16(v.x);
        h.y = (short)f32_to_bf16(v.y);
        h.z = (short)f32_to_bf16(v.z);
        h.w = (short)f32_to_bf16(v.w);
        dst[j] = h;
    }
}

// ---------------------------------------------------------------- GEMM 1: QKV
// Xb (bf16, 16384x512) @ W^T (W bf16 1536x512) + bias -> qkv bf16 (3,B,H,L,Dh)
// R8 schedule (best measured): 128x128, BK=64, 4 waves, dbuf + counted
// vmcnt(8) + raw s_barrier, XOR chunk swizzle (0 conflicts measured).
// R13: K-loop fully unrolled with compile-time buffer offsets (no pointer
// swaps) -> all LDS addresses are base+immediate, killing per-iter address
// VALU (R12 measured VALUBusy 43%); setprio(1) around MFMA clusters (T5).
__global__ __launch_bounds__(256) void gemm_qkv(
    const unsigned short* __restrict__ Xb,
    const unsigned short* __restrict__ W,
    const float* __restrict__ bias,
    unsigned short* __restrict__ qkvout)
{
    extern __shared__ __align__(16) unsigned short lds[];  // 65536 B
    // shorts: A(p) @ p*16384, B(p) @ p*16384 + 8192
    const int tid  = threadIdx.x;
    const int wv   = tid >> 6, ln = tid & 63;
    const int m0   = blockIdx.x * 128;
    const int n0   = blockIdx.y * 128;
    const int wm   = (wv >> 1) * 64;
    const int wn   = (wv & 1) * 64;
    const int lr   = ln & 15;          // fragment row/col
    const int lg   = ln >> 4;          // k-group (0..3)
    const int rgrp = ln >> 3;          // staging: row within 8-row chunk
    const int csw  = ((ln & 7) ^ rgrp) * 8;  // staging: swizzled source chunk

    float4_t acc[4][4];
    #pragma unroll
    for (int m = 0; m < 4; ++m)
        #pragma unroll
        for (int n = 0; n < 4; ++n)
            acc[m][n] = (float4_t){0.f, 0.f, 0.f, 0.f};

    #define STAGE(k0_, boff_) do {                                            \
        _Pragma("unroll")                                                     \
        for (int it_ = 0; it_ < 4; ++it_) {                                   \
            int ch_  = it_ * 4 + wv;                                          \
            int row_ = ch_ * 8 + rgrp;                                        \
            gload_lds16(Xb + (size_t)(m0 + row_) * KDIM + (k0_) + csw,        \
                        lds + (boff_) + ch_ * 8 * BK);                        \
            gload_lds16(W  + (size_t)(n0 + row_) * KDIM + (k0_) + csw,        \
                        lds + (boff_) + 8192 + ch_ * 8 * BK);                 \
        }                                                                     \
    } while (0)

    STAGE(0, 0);                       // prologue: 8 loads outstanding

    #pragma unroll
    for (int t = 0; t < 8; ++t) {
        const int cb = (t & 1) * 16384;        // compile-time per unrolled iter
        const int nb = ((t + 1) & 1) * 16384;
        if (t < 7) {
            STAGE((t + 1) * BK, nb);                          // 8 more in flight
            asm volatile("s_waitcnt vmcnt(8)" ::: "memory");  // tile t landed
        } else {
            asm volatile("s_waitcnt vmcnt(0)" ::: "memory");  // drain last tile
        }
        __builtin_amdgcn_s_barrier();                         // publish tile t

        short8 af[2][4], bfr[2][4];
        #pragma unroll
        for (int kk = 0; kk < 2; ++kk) {
            #pragma unroll
            for (int m = 0; m < 4; ++m) {
                int row = wm + m * 16 + lr;
                int c   = (kk * 4 + lg) ^ (row & 7);
                af[kk][m] = *reinterpret_cast<const short8*>(&lds[cb + row * BK + c * 8]);
            }
            #pragma unroll
            for (int n = 0; n < 4; ++n) {
                int row = wn + n * 16 + lr;
                int c   = (kk * 4 + lg) ^ (row & 7);
                bfr[kk][n] = *reinterpret_cast<const short8*>(&lds[cb + 8192 + row * BK + c * 8]);
            }
        }
        __builtin_amdgcn_s_setprio(1);
        #pragma unroll
        for (int kk = 0; kk < 2; ++kk)
            #pragma unroll
            for (int m = 0; m < 4; ++m)
                #pragma unroll
                for (int n = 0; n < 4; ++n)
                    acc[m][n] = __builtin_amdgcn_mfma_f32_16x16x32_bf16(
                        af[kk][m], bfr[kk][n], acc[m][n], 0, 0, 0);
        __builtin_amdgcn_s_setprio(0);

        if (t < 7) __builtin_amdgcn_s_barrier();  // WAR gate before refill
    }
    #undef STAGE

    // epilogue: bias, q-scale, scatter to (3,B,H,L,Dh) bf16
    const float qscale = 0.17677669529663687f;  // Dh^-0.5
    #pragma unroll
    for (int m = 0; m < 4; ++m) {
        #pragma unroll
        for (int n = 0; n < 4; ++n) {
            int gn    = n0 + wn + n * 16 + lr;
            int which = gn >> 9;            // 0=q 1=k 2=v
            int hh    = (gn >> 5) & 15;
            int dd    = gn & 31;
            float bsv = bias[gn];
            #pragma unroll
            for (int r = 0; r < 4; ++r) {
                int gm = m0 + wm + m * 16 + lg * 4 + r;
                float v = acc[m][n][r] + bsv;
                if (which == 0) v *= qscale;
                int b_ = gm >> 12, l = gm & 4095;
                size_t off = (((size_t)which * BATCH + b_) * HNUM + hh) *
                                 ((size_t)LSEQ * DH) + (size_t)l * DH + dd;
                qkvout[off] = f32_to_bf16(v);
            }
        }
    }
}

// ---------------------------------------------------------------- attention (MFMA)
// (R10 proven) Dh=32 == K of mfma_f32_16x16x32_bf16; see R10 notes.
__global__ __launch_bounds__(256) void natten_fwd(
    const unsigned short* __restrict__ qkv,  // (3,B,H,L,Dh) bf16
    const float* __restrict__ rpb,           // (16,25) f32
    unsigned short* __restrict__ ctx)        // (B,L,C) bf16
{
    #define NRP 280
    __shared__ __align__(16) unsigned short vt[DH * NRP];   // V^T [dim][key_rel]
    __shared__ __align__(16) unsigned short pl[4 * 16 * 32];// per-wave P [tok][key]
    __shared__ float rpb_s[25];

    const int t    = threadIdx.x;
    const int wv   = t >> 6, ln = t & 63;
    const int lblk = blockIdx.x & 15;
    const int bh   = blockIdx.x >> 4;
    const int hh   = bh & 15, b_ = bh >> 4;
    const int l0b  = lblk * 256;
    const int r0   = l0b - 6;

    const size_t plane = (size_t)LSEQ * DH;
    const size_t qbase = (((size_t)0 * BATCH + b_) * HNUM + hh) * plane;
    const size_t kbase = (((size_t)1 * BATCH + b_) * HNUM + hh) * plane;
    const size_t vbase = (((size_t)2 * BATCH + b_) * HNUM + hh) * plane;

    for (int kr = t; kr < 276; kr += 256) {
        int ka = min(max(r0 + kr, 0), LSEQ - 1);
        #pragma unroll
        for (int cq = 0; cq < 4; ++cq) {
            short8 v = *reinterpret_cast<const short8*>(&qkv[vbase + (size_t)ka * DH + cq * 8]);
            #pragma unroll
            for (int e = 0; e < 8; ++e)
                vt[(cq * 8 + e) * NRP + kr] = (unsigned short)v[e];
        }
    }
    if (t < 25) rpb_s[t] = rpb[hh * 25 + t];
    __syncthreads();

    const int g = ln >> 4;
    const int c = ln & 15;

    #pragma unroll
    for (int qi = 0; qi < 4; ++qi) {
        const int l0 = l0b + wv * 64 + qi * 16;
        const int k0 = l0 - 6;

        short8 qf = *reinterpret_cast<const short8*>(
            &qkv[qbase + (size_t)(l0 + c) * DH + g * 8]);
        int key0c = min(max(k0 + c, 0), LSEQ - 1);
        int key1c = min(max(k0 + 16 + c, 0), LSEQ - 1);
        short8 kf0 = *reinterpret_cast<const short8*>(
            &qkv[kbase + (size_t)key0c * DH + g * 8]);
        short8 kf1 = *reinterpret_cast<const short8*>(
            &qkv[kbase + (size_t)key1c * DH + g * 8]);
        float4_t s0 = (float4_t){0.f, 0.f, 0.f, 0.f};
        float4_t s1 = (float4_t){0.f, 0.f, 0.f, 0.f};
        s0 = __builtin_amdgcn_mfma_f32_16x16x32_bf16(qf, kf0, s0, 0, 0, 0);
        s1 = __builtin_amdgcn_mfma_f32_16x16x32_bf16(qf, kf1, s1, 0, 0, 0);

        const int ka0 = k0 + c;
        const int ka1 = k0 + 16 + c;
        #pragma unroll
        for (int r = 0; r < 4; ++r) {
            int tok = l0 + g * 4 + r;
            int st  = min(max(tok - NHALF, 0), LSEQ - KSZ);
            bool v0 = (ka0 >= st) && (ka0 < st + KSZ);
            bool v1 = (ka1 >= st) && (ka1 < st + KSZ);
            float b0 = rpb_s[min(max(ka0 - tok + 12, 0), 24)];
            float b1 = rpb_s[min(max(ka1 - tok + 12, 0), 24)];
            float x0 = v0 ? s0[r] + b0 : -1e30f;
            float x1 = v1 ? s1[r] + b1 : -1e30f;
            float m = fmaxf(x0, x1);
            #pragma unroll
            for (int d = 1; d < 16; d <<= 1) m = fmaxf(m, __shfl_xor(m, d));
            float e0 = v0 ? __expf(x0 - m) : 0.f;
            float e1 = v1 ? __expf(x1 - m) : 0.f;
            float s = e0 + e1;
            #pragma unroll
            for (int d = 1; d < 16; d <<= 1) s += __shfl_xor(s, d);
            float inv = 1.f / s;
            pl[wv * 512 + (g * 4 + r) * 32 + c]      = f32_to_bf16(e0 * inv);
            pl[wv * 512 + (g * 4 + r) * 32 + 16 + c] = f32_to_bf16(e1 * inv);
        }

        short8 pa = *reinterpret_cast<const short8*>(
            &pl[wv * 512 + c * 32 + g * 8]);
        int k0rel = l0 - l0b;
        short8 vb0 = *reinterpret_cast<const short8*>(
            &vt[c * NRP + k0rel + g * 8]);
        short8 vb1 = *reinterpret_cast<const short8*>(
            &vt[(16 + c) * NRP + k0rel + g * 8]);
        float4_t o0 = (float4_t){0.f, 0.f, 0.f, 0.f};
        float4_t o1 = (float4_t){0.f, 0.f, 0.f, 0.f};
        o0 = __builtin_amdgcn_mfma_f32_16x16x32_bf16(pa, vb0, o0, 0, 0, 0);
        o1 = __builtin_amdgcn_mfma_f32_16x16x32_bf16(pa, vb1, o1, 0, 0, 0);

        #pragma unroll
        for (int r = 0; r < 4; ++r) {
            size_t ob = ((size_t)(b_ * LSEQ + l0 + g * 4 + r)) * CCH + hh * DH;
            ctx[ob + c]      = f32_to_bf16(o0[r]);
            ctx[ob + 16 + c] = f32_to_bf16(o1[r]);
        }
    }
    #undef NRP
}

// ---------------------------------------------------------------- GEMM 2: proj
// ctx (bf16, 16384x512) @ W^T (W bf16 512x512) + bias -> out f32 (B,L,C)
// R8 schedule + R13 full unroll with static buffer offsets + setprio.
__global__ __launch_bounds__(256) void gemm_proj(
    const unsigned short* __restrict__ Xb,
    const unsigned short* __restrict__ W,
    const float* __restrict__ bias,
    float* __restrict__ out)
{
    extern __shared__ __align__(16) unsigned short lds[];  // 65536 B
    const int tid  = threadIdx.x;
    const int wv   = tid >> 6, ln = tid & 63;
    const int m0   = blockIdx.x * 128;
    const int n0   = blockIdx.y * 128;
    const int wm   = (wv >> 1) * 64;
    const int wn   = (wv & 1) * 64;
    const int lr   = ln & 15;
    const int lg   = ln >> 4;
    const int rgrp = ln >> 3;
    const int csw  = ((ln & 7) ^ rgrp) * 8;

    float4_t acc[4][4];
    #pragma unroll
    for (int m = 0; m < 4; ++m)
        #pragma unroll
        for (int n = 0; n < 4; ++n)
            acc[m][n] = (float4_t){0.f, 0.f, 0.f, 0.f};

    #define STAGEP(k0_, boff_) do {                                           \
        _Pragma("unroll")                                                     \
        for (int it_ = 0; it_ < 4; ++it_) {                                   \
            int ch_  = it_ * 4 + wv;                                          \
            int row_ = ch_ * 8 + rgrp;                                        \
            gload_lds16(Xb + (size_t)(m0 + row_) * KDIM + (k0_) + csw,        \
                        lds + (boff_) + ch_ * 8 * BK);                        \
            gload_lds16(W  + (size_t)(n0 + row_) * KDIM + (k0_) + csw,        \
                        lds + (boff_) + 8192 + ch_ * 8 * BK);                 \
        }                                                                     \
    } while (0)

    STAGEP(0, 0);

    #pragma unroll
    for (int t = 0; t < 8; ++t) {
        const int cb = (t & 1) * 16384;
        const int nb = ((t + 1) & 1) * 16384;
        if (t < 7) {
            STAGEP((t + 1) * BK, nb);
            asm volatile("s_waitcnt vmcnt(8)" ::: "memory");
        } else {
            asm volatile("s_waitcnt vmcnt(0)" ::: "memory");
        }
        __builtin_amdgcn_s_barrier();

        short8 af[2][4], bfr[2][4];
        #pragma unroll
        for (int kk = 0; kk < 2; ++kk) {
            #pragma unroll
            for (int m = 0; m < 4; ++m) {
                int row = wm + m * 16 + lr;
                int c   = (kk * 4 + lg) ^ (row & 7);
                af[kk][m] = *reinterpret_cast<const short8*>(&lds[cb + row * BK + c * 8]);
            }
            #pragma unroll
            for (int n = 0; n < 4; ++n) {
                int row = wn + n * 16 + lr;
                int c   = (kk * 4 + lg) ^ (row & 7);
                bfr[kk][n] = *reinterpret_cast<const short8*>(&lds[cb + 8192 + row * BK + c * 8]);
            }
        }
        __builtin_amdgcn_s_setprio(1);
        #pragma unroll
        for (int kk = 0; kk < 2; ++kk)
            #pragma unroll
            for (int m = 0; m < 4; ++m)
                #pragma unroll
                for (int n = 0; n < 4; ++n)
                    acc[m][n] = __builtin_amdgcn_mfma_f32_16x16x32_bf16(
                        af[kk][m], bfr[kk][n], acc[m][n], 0, 0, 0);
        __builtin_amdgcn_s_setprio(0);

        if (t < 7) __builtin_amdgcn_s_barrier();
    }
    #undef STAGEP

    #pragma unroll
    for (int m = 0; m < 4; ++m) {
        #pragma unroll
        for (int n = 0; n < 4; ++n) {
            int gn = n0 + wn + n * 16 + lr;
            float bsv = bias[gn];
            #pragma unroll
            for (int r = 0; r < 4; ++r) {
                int gm = m0 + wm + m * 16 + lg * 4 + r;
                out[(size_t)gm * CCH + gn] = acc[m][n][r] + bsv;
            }
        }
    }
}

// ---------------------------------------------------------------- launch
extern "C" void kernel_launch(void* const* d_in, const int* in_sizes, int n_in,
                              void* d_out, int out_size, void* d_ws, size_t ws_size,
                              hipStream_t stream) {
    const float* x      = (const float*)d_in[0];
    const float* qkv_w  = (const float*)d_in[1];
    const float* qkv_b  = (const float*)d_in[2];
    const float* rpb    = (const float*)d_in[3];
    const float* proj_w = (const float*)d_in[4];
    const float* proj_b = (const float*)d_in[5];
    float* out = (float*)d_out;
    char* ws = (char*)d_ws;

    // ws layout (bytes):
    //   qkv bf16 (3*B*H*L*Dh = 25165824 elems)   @ 0          : 50331648
    //   xb/ctx overlay (8388608 elems bf16)      @ 50331648   : 16777216
    //   qkv_w bf16 (786432 elems)                @ 67108864   :  1572864
    //   proj_w bf16 (262144 elems)               @ 68681728   :   524288
    unsigned short* qkv = (unsigned short*)(ws);
    unsigned short* xb  = (unsigned short*)(ws + 50331648);
    unsigned short* ctx = (unsigned short*)(ws + 50331648);
    unsigned short* wq  = (unsigned short*)(ws + 67108864);
    unsigned short* wp  = (unsigned short*)(ws + 68681728);

    cvt_all<<<2048, 256, 0, stream>>>(
        (const float4_t*)x,      (short4_t*)xb, M_TOT * KDIM / 4,
        (const float4_t*)qkv_w,  (short4_t*)wq, 786432 / 4,
        (const float4_t*)proj_w, (short4_t*)wp, 262144 / 4);

    dim3 g1(M_TOT / 128, N_QKV / 128);   // 128 x 12 = 1536 blocks
    gemm_qkv<<<g1, 256, 65536, stream>>>(xb, wq, qkv_b, qkv);

    natten_fwd<<<BATCH * HNUM * (LSEQ / 256), 256, 0, stream>>>(qkv, rpb, ctx);

    dim3 g2(M_TOT / 128, CCH / 128);     // 128 x 4 = 512 blocks
    gemm_proj<<<g2, 256, 65536, stream>>>(ctx, wp, proj_b, out);
}

// Round 14
// 76.735 us; speedup vs baseline: 1.0555x; 1.0555x over previous
//
#include <hip/hip_runtime.h>
#include <hip/hip_bf16.h>

// Problem constants (B=4, L=4096, C=512, H=16, Dh=32, K=13)
#define BATCH   4
#define LSEQ    4096
#define CCH     512
#define HNUM    16
#define DH      32
#define KSZ     13
#define NHALF   6           // K/2
#define M_TOT   16384       // B*L
#define N_QKV   1536        // 3*C
#define KDIM    512         // C
#define BK      64          // GEMM K-step (128B rows, XOR-swizzle domain of 8 chunks)

typedef __attribute__((ext_vector_type(8))) short  short8;
typedef __attribute__((ext_vector_type(4))) short  short4_t;
typedef __attribute__((ext_vector_type(4))) float  float4_t;

__device__ __forceinline__ unsigned short f32_to_bf16(float f) {
    union { float f; unsigned int u; } un; un.f = f;
    unsigned int u = un.u;
    u += 0x7FFFu + ((u >> 16) & 1u);   // RNE (inputs are finite)
    return (unsigned short)(u >> 16);
}
__device__ __forceinline__ float bf16_to_f32(unsigned short h) {
    union { unsigned int u; float f; } un; un.u = ((unsigned int)h) << 16;
    return un.f;
}

// async global(16B/lane) -> LDS; lds base must be wave-uniform, HW adds lane*16
__device__ __forceinline__ void gload_lds16(const unsigned short* g, unsigned short* l) {
    __builtin_amdgcn_global_load_lds(
        (const __attribute__((address_space(1))) unsigned int*)g,
        (__attribute__((address_space(3))) unsigned int*)l,
        16, 0, 0);
}

// ---------------------------------------------------------------- cvt f32->bf16
// one launch converts x, qkv_w, proj_w (grid-stride over the 3 ranges)
__global__ void cvt_all(const float4_t* __restrict__ xin,  short4_t* __restrict__ xo,  int nx,
                        const float4_t* __restrict__ w1in, short4_t* __restrict__ w1o, int n1,
                        const float4_t* __restrict__ w2in, short4_t* __restrict__ w2o, int n2) {
    int i = blockIdx.x * blockDim.x + threadIdx.x;
    int stride = gridDim.x * blockDim.x;
    int ntot = nx + n1 + n2;
    for (; i < ntot; i += stride) {
        const float4_t* src; short4_t* dst; int j;
        if (i < nx)            { src = xin;  dst = xo;  j = i; }
        else if (i < nx + n1)  { src = w1in; dst = w1o; j = i - nx; }
        else                   { src = w2in; dst = w2o; j = i - nx - n1; }
        float4_t v = src[j];
        short4_t h;
        h.x = (short)f32_to_bf16(v.x);
        h.y = (short)f32_to_bf16(v.y);
        h.z = (short)f32_to_bf16(v.z);
        h.w = (short)f32_to_bf16(v.w);
        dst[j] = h;
    }
}

// ---------------------------------------------------------------- GEMM 1: QKV
// R8 exact (best measured): 128x128, BK=64, 4 waves, dbuf + counted vmcnt(8),
// raw s_barrier, XOR chunk swizzle (0 conflicts measured).
__global__ __launch_bounds__(256) void gemm_qkv(
    const unsigned short* __restrict__ Xb,
    const unsigned short* __restrict__ W,
    const float* __restrict__ bias,
    unsigned short* __restrict__ qkvout)
{
    extern __shared__ __align__(16) unsigned short lds[];  // 65536 B
    const int tid  = threadIdx.x;
    const int wv   = tid >> 6, ln = tid & 63;
    const int m0   = blockIdx.x * 128;
    const int n0   = blockIdx.y * 128;
    const int wm   = (wv >> 1) * 64;
    const int wn   = (wv & 1) * 64;
    const int lr   = ln & 15;
    const int lg   = ln >> 4;
    const int rgrp = ln >> 3;
    const int csw  = ((ln & 7) ^ rgrp) * 8;

    float4_t acc[4][4];
    #pragma unroll
    for (int m = 0; m < 4; ++m)
        #pragma unroll
        for (int n = 0; n < 4; ++n)
            acc[m][n] = (float4_t){0.f, 0.f, 0.f, 0.f};

    #define STAGE(k0_, abuf_, bbuf_) do {                                     \
        _Pragma("unroll")                                                     \
        for (int it_ = 0; it_ < 4; ++it_) {                                   \
            int ch_  = it_ * 4 + wv;                                          \
            int row_ = ch_ * 8 + rgrp;                                        \
            gload_lds16(Xb + (size_t)(m0 + row_) * KDIM + (k0_) + csw,        \
                        (abuf_) + ch_ * 8 * BK);                              \
            gload_lds16(W  + (size_t)(n0 + row_) * KDIM + (k0_) + csw,        \
                        (bbuf_) + ch_ * 8 * BK);                              \
        }                                                                     \
    } while (0)

    unsigned short* Ac = lds;           unsigned short* Bc = lds + 8192;
    unsigned short* An = lds + 16384;   unsigned short* Bn = lds + 24576;

    STAGE(0, Ac, Bc);

    for (int t = 0; t < 8; ++t) {
        if (t < 7) {
            STAGE((t + 1) * BK, An, Bn);
            asm volatile("s_waitcnt vmcnt(8)" ::: "memory");
        } else {
            asm volatile("s_waitcnt vmcnt(0)" ::: "memory");
        }
        __builtin_amdgcn_s_barrier();

        short8 af[2][4], bfr[2][4];
        #pragma unroll
        for (int kk = 0; kk < 2; ++kk) {
            #pragma unroll
            for (int m = 0; m < 4; ++m) {
                int row = wm + m * 16 + lr;
                int c   = (kk * 4 + lg) ^ (row & 7);
                af[kk][m] = *reinterpret_cast<const short8*>(&Ac[row * BK + c * 8]);
            }
            #pragma unroll
            for (int n = 0; n < 4; ++n) {
                int row = wn + n * 16 + lr;
                int c   = (kk * 4 + lg) ^ (row & 7);
                bfr[kk][n] = *reinterpret_cast<const short8*>(&Bc[row * BK + c * 8]);
            }
        }
        #pragma unroll
        for (int kk = 0; kk < 2; ++kk)
            #pragma unroll
            for (int m = 0; m < 4; ++m)
                #pragma unroll
                for (int n = 0; n < 4; ++n)
                    acc[m][n] = __builtin_amdgcn_mfma_f32_16x16x32_bf16(
                        af[kk][m], bfr[kk][n], acc[m][n], 0, 0, 0);

        if (t < 7) __builtin_amdgcn_s_barrier();
        unsigned short* tA = Ac; Ac = An; An = tA;
        unsigned short* tB = Bc; Bc = Bn; Bn = tB;
    }
    #undef STAGE

    const float qscale = 0.17677669529663687f;  // Dh^-0.5
    #pragma unroll
    for (int m = 0; m < 4; ++m) {
        #pragma unroll
        for (int n = 0; n < 4; ++n) {
            int gn    = n0 + wn + n * 16 + lr;
            int which = gn >> 9;            // 0=q 1=k 2=v
            int hh    = (gn >> 5) & 15;
            int dd    = gn & 31;
            float bsv = bias[gn];
            #pragma unroll
            for (int r = 0; r < 4; ++r) {
                int gm = m0 + wm + m * 16 + lg * 4 + r;
                float v = acc[m][n][r] + bsv;
                if (which == 0) v *= qscale;
                int b_ = gm >> 12, l = gm & 4095;
                size_t off = (((size_t)which * BATCH + b_) * HNUM + hh) *
                                 ((size_t)LSEQ * DH) + (size_t)l * DH + dd;
                qkvout[off] = f32_to_bf16(v);
            }
        }
    }
}

// ---------------------------------------------------------------- attention (MFMA)
// Dh=32 == K of mfma_f32_16x16x32_bf16. Per 16-token q-tile: 13-wide band fits
// a 32-key window [k0, k0+32), k0 = l0-6 (unclamped -> 16-aligned rel offsets;
// OOB handled by clamped addresses + validity masks, p=0 at invalid keys).
__global__ __launch_bounds__(256) void natten_fwd(
    const unsigned short* __restrict__ qkv,  // (3,B,H,L,Dh) bf16
    const float* __restrict__ rpb,           // (16,25) f32
    unsigned short* __restrict__ ctx)        // (B,L,C) bf16
{
    #define NRP 280
    __shared__ __align__(16) unsigned short vt[DH * NRP];   // V^T [dim][key_rel]
    __shared__ __align__(16) unsigned short pl[4 * 16 * 32];// per-wave P [tok][key]
    __shared__ float rpb_s[25];

    const int t    = threadIdx.x;
    const int wv   = t >> 6, ln = t & 63;
    const int lblk = blockIdx.x & 15;
    const int bh   = blockIdx.x >> 4;
    const int hh   = bh & 15, b_ = bh >> 4;
    const int l0b  = lblk * 256;
    const int r0   = l0b - 6;

    const size_t plane = (size_t)LSEQ * DH;
    const size_t qbase = (((size_t)0 * BATCH + b_) * HNUM + hh) * plane;
    const size_t kbase = (((size_t)1 * BATCH + b_) * HNUM + hh) * plane;
    const size_t vbase = (((size_t)2 * BATCH + b_) * HNUM + hh) * plane;

    for (int kr = t; kr < 276; kr += 256) {
        int ka = min(max(r0 + kr, 0), LSEQ - 1);
        #pragma unroll
        for (int cq = 0; cq < 4; ++cq) {
            short8 v = *reinterpret_cast<const short8*>(&qkv[vbase + (size_t)ka * DH + cq * 8]);
            #pragma unroll
            for (int e = 0; e < 8; ++e)
                vt[(cq * 8 + e) * NRP + kr] = (unsigned short)v[e];
        }
    }
    if (t < 25) rpb_s[t] = rpb[hh * 25 + t];
    __syncthreads();

    const int g = ln >> 4;
    const int c = ln & 15;

    #pragma unroll
    for (int qi = 0; qi < 4; ++qi) {
        const int l0 = l0b + wv * 64 + qi * 16;
        const int k0 = l0 - 6;

        short8 qf = *reinterpret_cast<const short8*>(
            &qkv[qbase + (size_t)(l0 + c) * DH + g * 8]);
        int key0c = min(max(k0 + c, 0), LSEQ - 1);
        int key1c = min(max(k0 + 16 + c, 0), LSEQ - 1);
        short8 kf0 = *reinterpret_cast<const short8*>(
            &qkv[kbase + (size_t)key0c * DH + g * 8]);
        short8 kf1 = *reinterpret_cast<const short8*>(
            &qkv[kbase + (size_t)key1c * DH + g * 8]);
        float4_t s0 = (float4_t){0.f, 0.f, 0.f, 0.f};
        float4_t s1 = (float4_t){0.f, 0.f, 0.f, 0.f};
        s0 = __builtin_amdgcn_mfma_f32_16x16x32_bf16(qf, kf0, s0, 0, 0, 0);
        s1 = __builtin_amdgcn_mfma_f32_16x16x32_bf16(qf, kf1, s1, 0, 0, 0);

        const int ka0 = k0 + c;
        const int ka1 = k0 + 16 + c;
        #pragma unroll
        for (int r = 0; r < 4; ++r) {
            int tok = l0 + g * 4 + r;
            int st  = min(max(tok - NHALF, 0), LSEQ - KSZ);
            bool v0 = (ka0 >= st) && (ka0 < st + KSZ);
            bool v1 = (ka1 >= st) && (ka1 < st + KSZ);
            float b0 = rpb_s[min(max(ka0 - tok + 12, 0), 24)];
            float b1 = rpb_s[min(max(ka1 - tok + 12, 0), 24)];
            float x0 = v0 ? s0[r] + b0 : -1e30f;
            float x1 = v1 ? s1[r] + b1 : -1e30f;
            float m = fmaxf(x0, x1);
            #pragma unroll
            for (int d = 1; d < 16; d <<= 1) m = fmaxf(m, __shfl_xor(m, d));
            float e0 = v0 ? __expf(x0 - m) : 0.f;
            float e1 = v1 ? __expf(x1 - m) : 0.f;
            float s = e0 + e1;
            #pragma unroll
            for (int d = 1; d < 16; d <<= 1) s += __shfl_xor(s, d);
            float inv = 1.f / s;
            pl[wv * 512 + (g * 4 + r) * 32 + c]      = f32_to_bf16(e0 * inv);
            pl[wv * 512 + (g * 4 + r) * 32 + 16 + c] = f32_to_bf16(e1 * inv);
        }

        short8 pa = *reinterpret_cast<const short8*>(
            &pl[wv * 512 + c * 32 + g * 8]);
        int k0rel = l0 - l0b;
        short8 vb0 = *reinterpret_cast<const short8*>(
            &vt[c * NRP + k0rel + g * 8]);
        short8 vb1 = *reinterpret_cast<const short8*>(
            &vt[(16 + c) * NRP + k0rel + g * 8]);
        float4_t o0 = (float4_t){0.f, 0.f, 0.f, 0.f};
        float4_t o1 = (float4_t){0.f, 0.f, 0.f, 0.f};
        o0 = __builtin_amdgcn_mfma_f32_16x16x32_bf16(pa, vb0, o0, 0, 0, 0);
        o1 = __builtin_amdgcn_mfma_f32_16x16x32_bf16(pa, vb1, o1, 0, 0, 0);

        #pragma unroll
        for (int r = 0; r < 4; ++r) {
            size_t ob = ((size_t)(b_ * LSEQ + l0 + g * 4 + r)) * CCH + hh * DH;
            ctx[ob + c]      = f32_to_bf16(o0[r]);
            ctx[ob + 16 + c] = f32_to_bf16(o1[r]);
        }
    }
    #undef NRP
}

// ---------------------------------------------------------------- GEMM 2: proj
// (R8 proven) ctx @ Wp^T + bias -> out f32. 128x128, dbuf, counted vmcnt(8).
__global__ __launch_bounds__(256) void gemm_proj(
    const unsigned short* __restrict__ Xb,
    const unsigned short* __restrict__ W,
    const float* __restrict__ bias,
    float* __restrict__ out)
{
    extern __shared__ __align__(16) unsigned short lds[];  // 65536 B
    const int tid  = threadIdx.x;
    const int wv   = tid >> 6, ln = tid & 63;
    const int m0   = blockIdx.x * 128;
    const int n0   = blockIdx.y * 128;
    const int wm   = (wv >> 1) * 64;
    const int wn   = (wv & 1) * 64;
    const int lr   = ln & 15;
    const int lg   = ln >> 4;
    const int rgrp = ln >> 3;
    const int csw  = ((ln & 7) ^ rgrp) * 8;

    float4_t acc[4][4];
    #pragma unroll
    for (int m = 0; m < 4; ++m)
        #pragma unroll
        for (int n = 0; n < 4; ++n)
            acc[m][n] = (float4_t){0.f, 0.f, 0.f, 0.f};

    #define STAGEP(k0_, abuf_, bbuf_) do {                                    \
        _Pragma("unroll")                                                     \
        for (int it_ = 0; it_ < 4; ++it_) {                                   \
            int ch_  = it_ * 4 + wv;                                          \
            int row_ = ch_ * 8 + rgrp;                                        \
            gload_lds16(Xb + (size_t)(m0 + row_) * KDIM + (k0_) + csw,        \
                        (abuf_) + ch_ * 8 * BK);                              \
            gload_lds16(W  + (size_t)(n0 + row_) * KDIM + (k0_) + csw,        \
                        (bbuf_) + ch_ * 8 * BK);                              \
        }                                                                     \
    } while (0)

    unsigned short* Ac = lds;           unsigned short* Bc = lds + 8192;
    unsigned short* An = lds + 16384;   unsigned short* Bn = lds + 24576;

    STAGEP(0, Ac, Bc);

    for (int t = 0; t < 8; ++t) {
        if (t < 7) {
            STAGEP((t + 1) * BK, An, Bn);
            asm volatile("s_waitcnt vmcnt(8)" ::: "memory");
        } else {
            asm volatile("s_waitcnt vmcnt(0)" ::: "memory");
        }
        __builtin_amdgcn_s_barrier();

        short8 af[2][4], bfr[2][4];
        #pragma unroll
        for (int kk = 0; kk < 2; ++kk) {
            #pragma unroll
            for (int m = 0; m < 4; ++m) {
                int row = wm + m * 16 + lr;
                int c   = (kk * 4 + lg) ^ (row & 7);
                af[kk][m] = *reinterpret_cast<const short8*>(&Ac[row * BK + c * 8]);
            }
            #pragma unroll
            for (int n = 0; n < 4; ++n) {
                int row = wn + n * 16 + lr;
                int c   = (kk * 4 + lg) ^ (row & 7);
                bfr[kk][n] = *reinterpret_cast<const short8*>(&Bc[row * BK + c * 8]);
            }
        }
        #pragma unroll
        for (int kk = 0; kk < 2; ++kk)
            #pragma unroll
            for (int m = 0; m < 4; ++m)
                #pragma unroll
                for (int n = 0; n < 4; ++n)
                    acc[m][n] = __builtin_amdgcn_mfma_f32_16x16x32_bf16(
                        af[kk][m], bfr[kk][n], acc[m][n], 0, 0, 0);

        if (t < 7) __builtin_amdgcn_s_barrier();
        unsigned short* tA = Ac; Ac = An; An = tA;
        unsigned short* tB = Bc; Bc = Bn; Bn = tB;
    }
    #undef STAGEP

    #pragma unroll
    for (int m = 0; m < 4; ++m) {
        #pragma unroll
        for (int n = 0; n < 4; ++n) {
            int gn = n0 + wn + n * 16 + lr;
            float bsv = bias[gn];
            #pragma unroll
            for (int r = 0; r < 4; ++r) {
                int gm = m0 + wm + m * 16 + lg * 4 + r;
                out[(size_t)gm * CCH + gn] = acc[m][n][r] + bsv;
            }
        }
    }
}

// ---------------------------------------------------------------- launch
extern "C" void kernel_launch(void* const* d_in, const int* in_sizes, int n_in,
                              void* d_out, int out_size, void* d_ws, size_t ws_size,
                              hipStream_t stream) {
    const float* x      = (const float*)d_in[0];
    const float* qkv_w  = (const float*)d_in[1];
    const float* qkv_b  = (const float*)d_in[2];
    const float* rpb    = (const float*)d_in[3];
    const float* proj_w = (const float*)d_in[4];
    const float* proj_b = (const float*)d_in[5];
    float* out = (float*)d_out;
    char* ws = (char*)d_ws;

    // ws layout (bytes):
    //   qkv bf16 (3*B*H*L*Dh = 25165824 elems)   @ 0          : 50331648
    //   xb/ctx overlay (8388608 elems bf16)      @ 50331648   : 16777216
    //   qkv_w bf16 (786432 elems)                @ 67108864   :  1572864
    //   proj_w bf16 (262144 elems)               @ 68681728   :   524288
    unsigned short* qkv = (unsigned short*)(ws);
    unsigned short* xb  = (unsigned short*)(ws + 50331648);
    unsigned short* ctx = (unsigned short*)(ws + 50331648);
    unsigned short* wq  = (unsigned short*)(ws + 67108864);
    unsigned short* wp  = (unsigned short*)(ws + 68681728);

    cvt_all<<<2048, 256, 0, stream>>>(
        (const float4_t*)x,      (short4_t*)xb, M_TOT * KDIM / 4,
        (const float4_t*)qkv_w,  (short4_t*)wq, 786432 / 4,
        (const float4_t*)proj_w, (short4_t*)wp, 262144 / 4);

    dim3 g1(M_TOT / 128, N_QKV / 128);   // 128 x 12 = 1536 blocks
    gemm_qkv<<<g1, 256, 65536, stream>>>(xb, wq, qkv_b, qkv);

    natten_fwd<<<BATCH * HNUM * (LSEQ / 256), 256, 0, stream>>>(qkv, rpb, ctx);

    dim3 g2(M_TOT / 128, CCH / 128);     // 128 x 4 = 512 blocks
    gemm_proj<<<g2, 256, 65536, stream>>>(ctx, wp, proj_b, out);
}